// Round 4
// baseline (72.839 us; speedup 1.0000x reference)
//
#include <hip/hip_runtime.h>
#include <math.h>

typedef _Float16 f16;
typedef _Float16 f16x8 __attribute__((ext_vector_type(8)));
typedef float f32x4 __attribute__((ext_vector_type(4)));

#define NB 8192
#define LOGN (NB * 32)          // 262144 logits elements

// ---- ws byte layout ----
#define OFF_W0   0              // 4096 f32 (= g0 * sign(v0))
#define OFF_SC1  16384          // 4096 f32 scales for v1 rows
#define OFF_SC2  32768          // 2048 f32
#define OFF_SC3  40960          // 2048 f32
#define OFF_B1   49152          // 262144 f16 fragments [f][ks2][nt4][lane64][8]
#define OFF_B2   573440         // 131072 f16 [f][ks2][nt2][lane][8]
#define OFF_B3   835584         // 65536 f16 [f][nt2][lane][8]

// ---------------- prep 1: norms/scales ----------------
__global__ __launch_bounds__(256)
void prep_norm(const float* __restrict__ v0, const float* __restrict__ g0,
               const float* __restrict__ v1, const float* __restrict__ g1,
               const float* __restrict__ v2, const float* __restrict__ g2,
               const float* __restrict__ v3, const float* __restrict__ g3,
               float* __restrict__ ws) {
    int t = blockIdx.x * blockDim.x + threadIdx.x;
    if (t < 4096) {
        float v = v0[t];
        ws[OFF_W0 / 4 + t] = g0[t] * (v >= 0.f ? 1.f : -1.f);
    } else if (t < 8192) {
        int r = t - 4096;
        const float* vp = v1 + (size_t)r * 64;
        float ss = 0.f;
        #pragma unroll
        for (int i = 0; i < 16; ++i) {
            float4 x = *(const float4*)(vp + i * 4);
            ss += x.x * x.x + x.y * x.y + x.z * x.z + x.w * x.w;
        }
        ws[OFF_SC1 / 4 + r] = g1[r] * __frsqrt_rn(ss);
    } else if (t < 10240) {
        int r = t - 8192;
        const float* vp = v2 + (size_t)r * 64;
        float ss = 0.f;
        #pragma unroll
        for (int i = 0; i < 16; ++i) {
            float4 x = *(const float4*)(vp + i * 4);
            ss += x.x * x.x + x.y * x.y + x.z * x.z + x.w * x.w;
        }
        ws[OFF_SC2 / 4 + r] = g2[r] * __frsqrt_rn(ss);
    } else if (t < 12288) {
        int r = t - 10240;
        const float* vp = v3 + (size_t)r * 32;
        float ss = 0.f;
        #pragma unroll
        for (int i = 0; i < 8; ++i) {
            float4 x = *(const float4*)(vp + i * 4);
            ss += x.x * x.x + x.y * x.y + x.z * x.z + x.w * x.w;
        }
        ws[OFF_SC3 / 4 + r] = g3[r] * __frsqrt_rn(ss);
    }
}

// ---------------- prep 2: scatter weight-normed fp16 fragments ----------------
__global__ __launch_bounds__(256)
void prep_frag(const float* __restrict__ v1, const float* __restrict__ v2,
               const float* __restrict__ v3, const float* __restrict__ ws,
               f16* __restrict__ b1f, f16* __restrict__ b2f, f16* __restrict__ b3f) {
    int t = blockIdx.x * blockDim.x + threadIdx.x;   // 458752 total
    if (t < 262144) {
        int i = t & 7, lane = (t >> 3) & 63, nt = (t >> 9) & 3, ks = (t >> 11) & 1, f = t >> 12;
        int k = ks * 32 + ((lane >> 4) << 3) + i;
        int n = nt * 16 + (lane & 15);
        int r = f * 64 + n;
        b1f[t] = (f16)(v1[(size_t)r * 64 + k] * ws[OFF_SC1 / 4 + r]);
    } else if (t < 393216) {
        int t2 = t - 262144;
        int i = t2 & 7, lane = (t2 >> 3) & 63, nt = (t2 >> 9) & 1, ks = (t2 >> 10) & 1, f = t2 >> 11;
        int k = ks * 32 + ((lane >> 4) << 3) + i;
        int n = nt * 16 + (lane & 15);
        int r = f * 32 + n;
        b2f[t2] = (f16)(v2[(size_t)r * 64 + k] * ws[OFF_SC2 / 4 + r]);
    } else {
        int t3 = t - 393216;
        int i = t3 & 7, lane = (t3 >> 3) & 63, nt = (t3 >> 9) & 1, f = t3 >> 10;
        int k = ((lane >> 4) << 3) + i;
        int n = nt * 16 + (lane & 15);
        int r = f * 32 + n;
        b3f[t3] = (f16)(v3[(size_t)r * 32 + k] * ws[OFF_SC3 / 4 + r]);
    }
}

// ---------------- categorical features + logits base (runs BEFORE nam_real) ----------------
__global__ __launch_bounds__(256)
void nam_cat_base(const float* __restrict__ tab, const float* __restrict__ cat_linear,
                  const float* __restrict__ memb, const float* __restrict__ bias,
                  float* __restrict__ feat, float* __restrict__ logits) {
    __shared__ float cl[1024];
    __shared__ float mb[256];
    __shared__ float bs[32];
    for (int i = threadIdx.x; i < 1024; i += 256) cl[i] = cat_linear[i];
    if (threadIdx.x < 256) mb[threadIdx.x] = memb[threadIdx.x];
    if (threadIdx.x < 32) bs[threadIdx.x] = bias[threadIdx.x];
    __syncthreads();

    int t = blockIdx.x * blockDim.x + threadIdx.x;   // 8192*32
    int o = t & 31;
    int b = t >> 5;
    const float4* tb4 = (const float4*)(tab + (size_t)b * 192);
    float* fb = feat + (size_t)b * 3072 + 64 * 32 + o;
    float s = bs[o];
    #pragma unroll
    for (int q = 0; q < 8; ++q) {
        float4 v4 = tb4[16 + q];     // values cols 64+4q..
        float4 m4 = tb4[40 + q];     // missing cols 160+4q..
        float vv[4] = {v4.x, v4.y, v4.z, v4.w};
        float mm[4] = {m4.x, m4.y, m4.z, m4.w};
        #pragma unroll
        for (int e = 0; e < 4; ++e) {
            int fc = q * 4 + e;
            float r = cl[fc * 32 + o] * vv[e] * (1.f - mm[e]);
            if (fc < 8) r = fmaf(mb[fc * 32 + o], mm[e], r);
            fb[fc * 32] = r;
            s += r;
        }
    }
    logits[t] = s;   // bias + cat sum; real kernel atomically adds the rest
}

// ---------------- real features: MFMA MLP chain ----------------
// grid (64 batch-tiles, 8 feature-groups) x 256 thr. Wave-private: 32 rows/wave, 8 features.
__global__ __launch_bounds__(256, 2)
void nam_real_mfma(const float* __restrict__ tab, const float* __restrict__ w0,
                   const f16* __restrict__ b1f, const f16* __restrict__ b2f,
                   const f16* __restrict__ b3f,
                   const float* __restrict__ b0, const float* __restrict__ b1,
                   const float* __restrict__ b2, const float* __restrict__ memb,
                   float* __restrict__ feat, float* __restrict__ logits) {
    __shared__ char lds[4][8192];           // per-wave h1/h2 staging
    __shared__ float tv[128][8];            // tab values (this block's 8 features)
    __shared__ float tm[128][8];            // tab missing flags
    const int wave = threadIdx.x >> 6, lane = threadIdx.x & 63;
    const int lq = lane >> 4, lr = lane & 15;
    const int rowbase = blockIdx.x * 128 + wave * 32;
    const int f0 = blockIdx.y * 8;
    char* h1b = lds[wave];
    char* h2b = lds[wave] + 4096;

    // ---- coalesced tab staging: 128 rows x (8 val + 8 miss) ----
    #pragma unroll
    for (int it = 0; it < 8; ++it) {
        int g = it * 256 + threadIdx.x;     // 0..2047
        int row = g >> 4, w = g & 15;
        int col = (w < 8) ? (f0 + w) : (96 + f0 + (w - 8));
        float x = tab[(size_t)(blockIdx.x * 128 + row) * 192 + col];
        if (w < 8) tv[row][w] = x; else tm[row][w - 8] = x;
    }
    __syncthreads();

    // lacc[mt][nt][j]: running logits contribution for (row=rowbase+mt*16+lr, o=nt*16+lq*4+j)
    float lacc[2][2][4];
    #pragma unroll
    for (int mt = 0; mt < 2; ++mt)
        #pragma unroll
        for (int nt = 0; nt < 2; ++nt)
            #pragma unroll
            for (int j = 0; j < 4; ++j) lacc[mt][nt][j] = 0.f;

    #pragma unroll 1
    for (int fi = 0; fi < 8; ++fi) {
        const int f = f0 + fi;

        // ---- B fragments (coalesced 16B/lane, L2-resident) ----
        f16x8 B1[2][4], B2[2][2], B3[2];
        {
            const f16* p1 = b1f + f * 4096 + lane * 8;
            #pragma unroll
            for (int ks = 0; ks < 2; ++ks)
                #pragma unroll
                for (int nt = 0; nt < 4; ++nt)
                    B1[ks][nt] = *(const f16x8*)(p1 + ks * 2048 + nt * 512);
            const f16* p2 = b2f + f * 2048 + lane * 8;
            #pragma unroll
            for (int ks = 0; ks < 2; ++ks)
                #pragma unroll
                for (int nt = 0; nt < 2; ++nt)
                    B2[ks][nt] = *(const f16x8*)(p2 + ks * 1024 + nt * 512);
            const f16* p3 = b3f + f * 1024 + lane * 8;
            #pragma unroll
            for (int nt = 0; nt < 2; ++nt)
                B3[nt] = *(const f16x8*)(p3 + nt * 512);
        }

        // ---- biases / per-row inputs (from LDS) ----
        float b1v[4], b2v[2];
        #pragma unroll
        for (int nt = 0; nt < 4; ++nt) b1v[nt] = b1[f * 64 + nt * 16 + lr];
        #pragma unroll
        for (int nt = 0; nt < 2; ++nt) b2v[nt] = b2[f * 32 + nt * 16 + lr];
        float vmt[2], msr[2];
        #pragma unroll
        for (int mt = 0; mt < 2; ++mt) {
            vmt[mt] = tv[wave * 32 + mt * 16 + lr][fi];
            msr[mt] = tm[wave * 32 + mt * 16 + lr][fi];   // per-lane row mask (for transposed epilogue)
        }

        // ---- layer 0: build A fragments in registers (w0 = +/- g0) ----
        f16x8 A0[2][2];
        #pragma unroll
        for (int ks = 0; ks < 2; ++ks) {
            float w0v[8], b0v[8];
            *(float4*)&w0v[0] = *(const float4*)(w0 + f * 64 + ks * 32 + lq * 8);
            *(float4*)&w0v[4] = *(const float4*)(w0 + f * 64 + ks * 32 + lq * 8 + 4);
            *(float4*)&b0v[0] = *(const float4*)(b0 + f * 64 + ks * 32 + lq * 8);
            *(float4*)&b0v[4] = *(const float4*)(b0 + f * 64 + ks * 32 + lq * 8 + 4);
            #pragma unroll
            for (int mt = 0; mt < 2; ++mt)
                #pragma unroll
                for (int i = 0; i < 8; ++i)
                    A0[mt][ks][i] = (f16)fmaxf(fmaf(vmt[mt], w0v[i], b0v[i]), 0.f);
        }

        // ---- layer 1: [32x64] = A0[32x64] * W1^T ----
        f32x4 acc1[2][4];
        #pragma unroll
        for (int mt = 0; mt < 2; ++mt)
            #pragma unroll
            for (int nt = 0; nt < 4; ++nt) acc1[mt][nt] = (f32x4){0.f, 0.f, 0.f, 0.f};
        #pragma unroll
        for (int ks = 0; ks < 2; ++ks)
            #pragma unroll
            for (int nt = 0; nt < 4; ++nt)
                #pragma unroll
                for (int mt = 0; mt < 2; ++mt)
                    acc1[mt][nt] = __builtin_amdgcn_mfma_f32_16x16x32_f16(A0[mt][ks], B1[ks][nt], acc1[mt][nt], 0, 0, 0);
        // relu+bias -> fp16 -> swizzled LDS
        #pragma unroll
        for (int mt = 0; mt < 2; ++mt)
            #pragma unroll
            for (int nt = 0; nt < 4; ++nt) {
                int n = nt * 16 + lr;
                int colb = ((n >> 3) << 4) + ((n & 7) << 1);
                #pragma unroll
                for (int j = 0; j < 4; ++j) {
                    int row = mt * 16 + lq * 4 + j;
                    int byte = ((row << 7) + colb) ^ ((row & 7) << 4);
                    *(f16*)(h1b + byte) = (f16)fmaxf(acc1[mt][nt][j] + b1v[nt], 0.f);
                }
            }

        // ---- layer 2: [32x32] = H1[32x64] * W2^T ----
        f16x8 A1[2][2];
        #pragma unroll
        for (int mt = 0; mt < 2; ++mt)
            #pragma unroll
            for (int ks = 0; ks < 2; ++ks) {
                int row = mt * 16 + lr;
                int byte = ((row << 7) + ((ks * 4 + lq) << 4)) ^ ((row & 7) << 4);
                A1[mt][ks] = *(const f16x8*)(h1b + byte);
            }
        f32x4 acc2[2][2];
        #pragma unroll
        for (int mt = 0; mt < 2; ++mt)
            #pragma unroll
            for (int nt = 0; nt < 2; ++nt) acc2[mt][nt] = (f32x4){0.f, 0.f, 0.f, 0.f};
        #pragma unroll
        for (int ks = 0; ks < 2; ++ks)
            #pragma unroll
            for (int nt = 0; nt < 2; ++nt)
                #pragma unroll
                for (int mt = 0; mt < 2; ++mt)
                    acc2[mt][nt] = __builtin_amdgcn_mfma_f32_16x16x32_f16(A1[mt][ks], B2[ks][nt], acc2[mt][nt], 0, 0, 0);
        #pragma unroll
        for (int mt = 0; mt < 2; ++mt)
            #pragma unroll
            for (int nt = 0; nt < 2; ++nt) {
                int n = nt * 16 + lr;
                int colb = ((n >> 3) << 4) + ((n & 7) << 1);
                #pragma unroll
                for (int j = 0; j < 4; ++j) {
                    int row = mt * 16 + lq * 4 + j;
                    int byte = ((row << 7) + colb) ^ ((row & 7) << 4);
                    *(f16*)(h2b + byte) = (f16)fmaxf(acc2[mt][nt][j] + b2v[nt], 0.f);
                }
            }

        // ---- layer 3 TRANSPOSED: D[o][brow] = W3 * H2^T ----
        // A-operand = B3[nt] (lane&15 -> o), B-operand = A2[mt] (lane&15 -> brow).
        // D: col=lane&15=brow, rows=lq*4+j = 4 CONTIGUOUS o -> float4 stores.
        f16x8 A2[2];
        #pragma unroll
        for (int mt = 0; mt < 2; ++mt) {
            int row = mt * 16 + lr;
            int byte = ((row << 7) + (lq << 4)) ^ ((row & 7) << 4);
            A2[mt] = *(const f16x8*)(h2b + byte);
        }
        f32x4 accT[2][2];
        #pragma unroll
        for (int nt = 0; nt < 2; ++nt)
            #pragma unroll
            for (int mt = 0; mt < 2; ++mt) accT[nt][mt] = (f32x4){0.f, 0.f, 0.f, 0.f};
        #pragma unroll
        for (int nt = 0; nt < 2; ++nt)
            #pragma unroll
            for (int mt = 0; mt < 2; ++mt)
                accT[nt][mt] = __builtin_amdgcn_mfma_f32_16x16x32_f16(B3[nt], A2[mt], accT[nt][mt], 0, 0, 0);

        // ---- epilogue: mask (per-lane row), missing-emb (contiguous o), float4 store ----
        const bool hasemb = (f < 16);
        float4 e[2] = {{0,0,0,0},{0,0,0,0}};
        if (hasemb) {
            #pragma unroll
            for (int nt = 0; nt < 2; ++nt)
                e[nt] = *(const float4*)(memb + (8 + f) * 32 + nt * 16 + lq * 4);
        }
        #pragma unroll
        for (int mt = 0; mt < 2; ++mt) {
            const int row = rowbase + mt * 16 + lr;
            const float m = msr[mt];
            const float keep = 1.f - m;
            float* dst = feat + (size_t)row * 3072 + f * 32 + lq * 4;
            #pragma unroll
            for (int nt = 0; nt < 2; ++nt) {
                float4 v;
                v.x = accT[nt][mt][0] * keep;
                v.y = accT[nt][mt][1] * keep;
                v.z = accT[nt][mt][2] * keep;
                v.w = accT[nt][mt][3] * keep;
                if (hasemb) {
                    v.x = fmaf(e[nt].x, m, v.x);
                    v.y = fmaf(e[nt].y, m, v.y);
                    v.z = fmaf(e[nt].z, m, v.z);
                    v.w = fmaf(e[nt].w, m, v.w);
                }
                *(float4*)(dst + nt * 16) = v;
                lacc[mt][nt][0] += v.x;
                lacc[mt][nt][1] += v.y;
                lacc[mt][nt][2] += v.z;
                lacc[mt][nt][3] += v.w;
            }
        }
    }

    // ---- logits: atomic add of this feature-group's contribution ----
    #pragma unroll
    for (int mt = 0; mt < 2; ++mt) {
        const int row = rowbase + mt * 16 + lr;
        float* lp = logits + (size_t)row * 32 + lq * 4;
        #pragma unroll
        for (int nt = 0; nt < 2; ++nt)
            #pragma unroll
            for (int j = 0; j < 4; ++j)
                atomicAdd(lp + nt * 16 + j, lacc[mt][nt][j]);
    }
}

extern "C" void kernel_launch(void* const* d_in, const int* in_sizes, int n_in,
                              void* d_out, int out_size, void* d_ws, size_t ws_size,
                              hipStream_t stream) {
    const float* tab        = (const float*)d_in[0];
    const float* v0         = (const float*)d_in[1];
    const float* g0         = (const float*)d_in[2];
    const float* b0         = (const float*)d_in[3];
    const float* v1         = (const float*)d_in[4];
    const float* g1         = (const float*)d_in[5];
    const float* b1         = (const float*)d_in[6];
    const float* v2         = (const float*)d_in[7];
    const float* g2         = (const float*)d_in[8];
    const float* b2         = (const float*)d_in[9];
    const float* v3         = (const float*)d_in[10];
    const float* g3         = (const float*)d_in[11];
    const float* cat_linear = (const float*)d_in[12];
    const float* memb       = (const float*)d_in[13];
    const float* bias       = (const float*)d_in[14];

    float* out    = (float*)d_out;
    float* logits = out;                 // [8192][32]
    float* feat   = out + LOGN;          // [8192][96][32]

    float* ws   = (float*)d_ws;
    float* w0   = (float*)((char*)d_ws + OFF_W0);
    f16*   b1f  = (f16*)((char*)d_ws + OFF_B1);
    f16*   b2f  = (f16*)((char*)d_ws + OFF_B2);
    f16*   b3f  = (f16*)((char*)d_ws + OFF_B3);

    prep_norm<<<48, 256, 0, stream>>>(v0, g0, v1, g1, v2, g2, v3, g3, ws);
    prep_frag<<<1792, 256, 0, stream>>>(v1, v2, v3, ws, b1f, b2f, b3f);

    // cat kernel FIRST: writes logits = bias + cat contribution (deterministic base),
    // then nam_real atomically accumulates the 8 real feature groups.
    nam_cat_base<<<LOGN / 256, 256, 0, stream>>>(tab, cat_linear, memb, bias, feat, logits);

    dim3 gr(64, 8);
    nam_real_mfma<<<gr, 256, 0, stream>>>(tab, w0, b1f, b2f, b3f, b0, b1, b2, memb, feat, logits);
}

// Round 5
// 58.930 us; speedup vs baseline: 1.2360x; 1.2360x over previous
//
#include <hip/hip_runtime.h>
#include <math.h>

typedef _Float16 f16;
typedef _Float16 f16x8 __attribute__((ext_vector_type(8)));
typedef float f32x4 __attribute__((ext_vector_type(4)));

#define NB 8192
#define LOGN (NB * 32)

// ---- ws byte layout (weights only) ----
#define OFF_W0   0              // 4096 f32 (= g0 * sign(v0))
#define OFF_SC1  16384          // 4096 f32 scales for v1 rows
#define OFF_SC2  32768          // 2048 f32
#define OFF_SC3  40960          // 2048 f32
#define OFF_B1   49152          // 262144 f16 fragments [f][ks2][nt4][lane64][8]
#define OFF_B2   573440         // 131072 f16 [f][ks2][nt2][lane][8]
#define OFF_B3   835584         // 65536 f16 [f][nt2][lane][8]

// ---------------- prep 1: norms/scales ----------------
__global__ __launch_bounds__(256)
void prep_norm(const float* __restrict__ v0, const float* __restrict__ g0,
               const float* __restrict__ v1, const float* __restrict__ g1,
               const float* __restrict__ v2, const float* __restrict__ g2,
               const float* __restrict__ v3, const float* __restrict__ g3,
               float* __restrict__ ws) {
    int t = blockIdx.x * blockDim.x + threadIdx.x;
    if (t < 4096) {
        float v = v0[t];
        ws[OFF_W0 / 4 + t] = g0[t] * (v >= 0.f ? 1.f : -1.f);
    } else if (t < 8192) {
        int r = t - 4096;
        const float* vp = v1 + (size_t)r * 64;
        float ss = 0.f;
        #pragma unroll
        for (int i = 0; i < 16; ++i) {
            float4 x = *(const float4*)(vp + i * 4);
            ss += x.x * x.x + x.y * x.y + x.z * x.z + x.w * x.w;
        }
        ws[OFF_SC1 / 4 + r] = g1[r] * __frsqrt_rn(ss);
    } else if (t < 10240) {
        int r = t - 8192;
        const float* vp = v2 + (size_t)r * 64;
        float ss = 0.f;
        #pragma unroll
        for (int i = 0; i < 16; ++i) {
            float4 x = *(const float4*)(vp + i * 4);
            ss += x.x * x.x + x.y * x.y + x.z * x.z + x.w * x.w;
        }
        ws[OFF_SC2 / 4 + r] = g2[r] * __frsqrt_rn(ss);
    } else if (t < 12288) {
        int r = t - 10240;
        const float* vp = v3 + (size_t)r * 32;
        float ss = 0.f;
        #pragma unroll
        for (int i = 0; i < 8; ++i) {
            float4 x = *(const float4*)(vp + i * 4);
            ss += x.x * x.x + x.y * x.y + x.z * x.z + x.w * x.w;
        }
        ws[OFF_SC3 / 4 + r] = g3[r] * __frsqrt_rn(ss);
    }
}

// ---------------- prep 2: scatter weight-normed fp16 fragments ----------------
__global__ __launch_bounds__(256)
void prep_frag(const float* __restrict__ v1, const float* __restrict__ v2,
               const float* __restrict__ v3, const float* __restrict__ ws,
               f16* __restrict__ b1f, f16* __restrict__ b2f, f16* __restrict__ b3f) {
    int t = blockIdx.x * blockDim.x + threadIdx.x;   // 458752 total
    if (t < 262144) {
        int i = t & 7, lane = (t >> 3) & 63, nt = (t >> 9) & 3, ks = (t >> 11) & 1, f = t >> 12;
        int k = ks * 32 + ((lane >> 4) << 3) + i;
        int n = nt * 16 + (lane & 15);
        int r = f * 64 + n;
        b1f[t] = (f16)(v1[(size_t)r * 64 + k] * ws[OFF_SC1 / 4 + r]);
    } else if (t < 393216) {
        int t2 = t - 262144;
        int i = t2 & 7, lane = (t2 >> 3) & 63, nt = (t2 >> 9) & 1, ks = (t2 >> 10) & 1, f = t2 >> 11;
        int k = ks * 32 + ((lane >> 4) << 3) + i;
        int n = nt * 16 + (lane & 15);
        int r = f * 32 + n;
        b2f[t2] = (f16)(v2[(size_t)r * 64 + k] * ws[OFF_SC2 / 4 + r]);
    } else {
        int t3 = t - 393216;
        int i = t3 & 7, lane = (t3 >> 3) & 63, nt = (t3 >> 9) & 1, f = t3 >> 10;
        int k = ((lane >> 4) << 3) + i;
        int n = nt * 16 + (lane & 15);
        int r = f * 32 + n;
        b3f[t3] = (f16)(v3[(size_t)r * 32 + k] * ws[OFF_SC3 / 4 + r]);
    }
}

// ---------------- fused: real MLPs + cat + logits, one block owns 32 rows ----------------
// grid 256 blocks x 256 thr (4 waves). Wave w handles features [w*16, w*16+16) for ALL 32 rows.
// Logits reduced in-block via LDS; cat features + logits written in the tail.
__global__ __launch_bounds__(256, 2)
void nam_fused(const float* __restrict__ tab, const float* __restrict__ w0,
               const f16* __restrict__ b1f, const f16* __restrict__ b2f,
               const f16* __restrict__ b3f,
               const float* __restrict__ b0, const float* __restrict__ b1,
               const float* __restrict__ b2, const float* __restrict__ memb,
               const float* __restrict__ cat_linear, const float* __restrict__ bias,
               float* __restrict__ feat, float* __restrict__ logits) {
    __shared__ char lds[4][8192];        // per-wave h1/h2 staging (XOR-swizzled, 128B pitch)
    __shared__ f16 tv[32][98];           // values  cols 0..95 (pitch 98: odd dword stride)
    __shared__ f16 tm[32][98];           // missing cols 0..95
    __shared__ float lsum[32][36];       // per-(row,o) real-feature logits partials

    const int wave = threadIdx.x >> 6, lane = threadIdx.x & 63;
    const int lq = lane >> 4, lr = lane & 15;
    const int rowbase = blockIdx.x * 32;
    const int f0 = wave * 16;
    char* h1b = lds[wave];
    char* h2b = lds[wave] + 4096;

    // ---- zero lsum ----
    for (int i = threadIdx.x; i < 32 * 36; i += 256)
        (&lsum[0][0])[i] = 0.f;

    // ---- stage tab rows [rowbase, +32): 48 float4 per row ----
    #pragma unroll
    for (int it = 0; it < 6; ++it) {
        int g = it * 256 + threadIdx.x;          // 0..1535
        int row = g / 48, q = g - row * 48;      // q: which float4 in the row
        float4 x = *(const float4*)(tab + (size_t)(rowbase + row) * 192 + q * 4);
        int c = q * 4;
        if (c < 96) {
            tv[row][c + 0] = (f16)x.x; tv[row][c + 1] = (f16)x.y;
            tv[row][c + 2] = (f16)x.z; tv[row][c + 3] = (f16)x.w;
        } else {
            int cm = c - 96;
            tm[row][cm + 0] = (f16)x.x; tm[row][cm + 1] = (f16)x.y;
            tm[row][cm + 2] = (f16)x.z; tm[row][cm + 3] = (f16)x.w;
        }
    }
    __syncthreads();

    // lacc[mt][nt][j]: logits contribution for (row = mt*16+lr, o = nt*16+lq*4+j)
    float lacc[2][2][4];
    #pragma unroll
    for (int mt = 0; mt < 2; ++mt)
        #pragma unroll
        for (int nt = 0; nt < 2; ++nt)
            #pragma unroll
            for (int j = 0; j < 4; ++j) lacc[mt][nt][j] = 0.f;

    #pragma unroll 1
    for (int fi = 0; fi < 16; ++fi) {
        const int f = f0 + fi;

        // ---- B fragments (coalesced 16B/lane, L2-resident) ----
        f16x8 B1[2][4], B2[2][2], B3[2];
        {
            const f16* p1 = b1f + f * 4096 + lane * 8;
            #pragma unroll
            for (int ks = 0; ks < 2; ++ks)
                #pragma unroll
                for (int nt = 0; nt < 4; ++nt)
                    B1[ks][nt] = *(const f16x8*)(p1 + ks * 2048 + nt * 512);
            const f16* p2 = b2f + f * 2048 + lane * 8;
            #pragma unroll
            for (int ks = 0; ks < 2; ++ks)
                #pragma unroll
                for (int nt = 0; nt < 2; ++nt)
                    B2[ks][nt] = *(const f16x8*)(p2 + ks * 1024 + nt * 512);
            const f16* p3 = b3f + f * 1024 + lane * 8;
            #pragma unroll
            for (int nt = 0; nt < 2; ++nt)
                B3[nt] = *(const f16x8*)(p3 + nt * 512);
        }

        // ---- biases / per-row inputs ----
        float b1v[4], b2v[2];
        #pragma unroll
        for (int nt = 0; nt < 4; ++nt) b1v[nt] = b1[f * 64 + nt * 16 + lr];
        #pragma unroll
        for (int nt = 0; nt < 2; ++nt) b2v[nt] = b2[f * 32 + nt * 16 + lr];
        float vmt[2], msr[2];
        #pragma unroll
        for (int mt = 0; mt < 2; ++mt) {
            vmt[mt] = (float)tv[mt * 16 + lr][f];
            msr[mt] = (float)tm[mt * 16 + lr][f];
        }

        // ---- layer 0: build A fragments (w0 = +/- g0) ----
        f16x8 A0[2][2];
        #pragma unroll
        for (int ks = 0; ks < 2; ++ks) {
            float w0v[8], b0v[8];
            *(float4*)&w0v[0] = *(const float4*)(w0 + f * 64 + ks * 32 + lq * 8);
            *(float4*)&w0v[4] = *(const float4*)(w0 + f * 64 + ks * 32 + lq * 8 + 4);
            *(float4*)&b0v[0] = *(const float4*)(b0 + f * 64 + ks * 32 + lq * 8);
            *(float4*)&b0v[4] = *(const float4*)(b0 + f * 64 + ks * 32 + lq * 8 + 4);
            #pragma unroll
            for (int mt = 0; mt < 2; ++mt)
                #pragma unroll
                for (int i = 0; i < 8; ++i)
                    A0[mt][ks][i] = (f16)fmaxf(fmaf(vmt[mt], w0v[i], b0v[i]), 0.f);
        }

        // ---- layer 1: [32x64] = A0 * W1^T ----
        f32x4 acc1[2][4];
        #pragma unroll
        for (int mt = 0; mt < 2; ++mt)
            #pragma unroll
            for (int nt = 0; nt < 4; ++nt) acc1[mt][nt] = (f32x4){0.f, 0.f, 0.f, 0.f};
        #pragma unroll
        for (int ks = 0; ks < 2; ++ks)
            #pragma unroll
            for (int nt = 0; nt < 4; ++nt)
                #pragma unroll
                for (int mt = 0; mt < 2; ++mt)
                    acc1[mt][nt] = __builtin_amdgcn_mfma_f32_16x16x32_f16(A0[mt][ks], B1[ks][nt], acc1[mt][nt], 0, 0, 0);
        #pragma unroll
        for (int mt = 0; mt < 2; ++mt)
            #pragma unroll
            for (int nt = 0; nt < 4; ++nt) {
                int n = nt * 16 + lr;
                int colb = ((n >> 3) << 4) + ((n & 7) << 1);
                #pragma unroll
                for (int j = 0; j < 4; ++j) {
                    int row = mt * 16 + lq * 4 + j;
                    int byte = ((row << 7) + colb) ^ ((row & 7) << 4);
                    *(f16*)(h1b + byte) = (f16)fmaxf(acc1[mt][nt][j] + b1v[nt], 0.f);
                }
            }

        // ---- layer 2: [32x32] = H1 * W2^T ----
        f16x8 A1[2][2];
        #pragma unroll
        for (int mt = 0; mt < 2; ++mt)
            #pragma unroll
            for (int ks = 0; ks < 2; ++ks) {
                int row = mt * 16 + lr;
                int byte = ((row << 7) + ((ks * 4 + lq) << 4)) ^ ((row & 7) << 4);
                A1[mt][ks] = *(const f16x8*)(h1b + byte);
            }
        f32x4 acc2[2][2];
        #pragma unroll
        for (int mt = 0; mt < 2; ++mt)
            #pragma unroll
            for (int nt = 0; nt < 2; ++nt) acc2[mt][nt] = (f32x4){0.f, 0.f, 0.f, 0.f};
        #pragma unroll
        for (int ks = 0; ks < 2; ++ks)
            #pragma unroll
            for (int nt = 0; nt < 2; ++nt)
                #pragma unroll
                for (int mt = 0; mt < 2; ++mt)
                    acc2[mt][nt] = __builtin_amdgcn_mfma_f32_16x16x32_f16(A1[mt][ks], B2[ks][nt], acc2[mt][nt], 0, 0, 0);
        #pragma unroll
        for (int mt = 0; mt < 2; ++mt)
            #pragma unroll
            for (int nt = 0; nt < 2; ++nt) {
                int n = nt * 16 + lr;
                int colb = ((n >> 3) << 4) + ((n & 7) << 1);
                #pragma unroll
                for (int j = 0; j < 4; ++j) {
                    int row = mt * 16 + lq * 4 + j;
                    int byte = ((row << 7) + colb) ^ ((row & 7) << 4);
                    *(f16*)(h2b + byte) = (f16)fmaxf(acc2[mt][nt][j] + b2v[nt], 0.f);
                }
            }

        // ---- layer 3 TRANSPOSED: D[o][brow] = W3 * H2^T -> float4 stores ----
        f16x8 A2[2];
        #pragma unroll
        for (int mt = 0; mt < 2; ++mt) {
            int row = mt * 16 + lr;
            int byte = ((row << 7) + (lq << 4)) ^ ((row & 7) << 4);
            A2[mt] = *(const f16x8*)(h2b + byte);
        }
        f32x4 accT[2][2];
        #pragma unroll
        for (int nt = 0; nt < 2; ++nt)
            #pragma unroll
            for (int mt = 0; mt < 2; ++mt) accT[nt][mt] = (f32x4){0.f, 0.f, 0.f, 0.f};
        #pragma unroll
        for (int nt = 0; nt < 2; ++nt)
            #pragma unroll
            for (int mt = 0; mt < 2; ++mt)
                accT[nt][mt] = __builtin_amdgcn_mfma_f32_16x16x32_f16(B3[nt], A2[mt], accT[nt][mt], 0, 0, 0);

        // ---- epilogue: mask, missing-emb, float4 store, local logits acc ----
        const bool hasemb = (f < 16);
        float4 e[2] = {{0, 0, 0, 0}, {0, 0, 0, 0}};
        if (hasemb) {
            #pragma unroll
            for (int nt = 0; nt < 2; ++nt)
                e[nt] = *(const float4*)(memb + (8 + f) * 32 + nt * 16 + lq * 4);
        }
        #pragma unroll
        for (int mt = 0; mt < 2; ++mt) {
            const int row = rowbase + mt * 16 + lr;
            const float m = msr[mt];
            const float keep = 1.f - m;
            float* dst = feat + (size_t)row * 3072 + f * 32 + lq * 4;
            #pragma unroll
            for (int nt = 0; nt < 2; ++nt) {
                float4 v;
                v.x = accT[nt][mt][0] * keep;
                v.y = accT[nt][mt][1] * keep;
                v.z = accT[nt][mt][2] * keep;
                v.w = accT[nt][mt][3] * keep;
                if (hasemb) {
                    v.x = fmaf(e[nt].x, m, v.x);
                    v.y = fmaf(e[nt].y, m, v.y);
                    v.z = fmaf(e[nt].z, m, v.z);
                    v.w = fmaf(e[nt].w, m, v.w);
                }
                *(float4*)(dst + nt * 16) = v;
                lacc[mt][nt][0] += v.x;
                lacc[mt][nt][1] += v.y;
                lacc[mt][nt][2] += v.z;
                lacc[mt][nt][3] += v.w;
            }
        }
    }

    // ---- reduce real logits across the 4 waves (LDS atomics, block-local) ----
    #pragma unroll
    for (int mt = 0; mt < 2; ++mt)
        #pragma unroll
        for (int nt = 0; nt < 2; ++nt)
            #pragma unroll
            for (int j = 0; j < 4; ++j)
                atomicAdd(&lsum[mt * 16 + lr][nt * 16 + lq * 4 + j], lacc[mt][nt][j]);
    __syncthreads();

    // ---- tail: cat features + final logits (thread = (row, 4 contiguous o)) ----
    {
        const int row = threadIdx.x >> 3;            // 0..31
        const int o4 = (threadIdx.x & 7) * 4;        // 0..28
        const int grow = rowbase + row;
        float4 s = *(const float4*)(bias + o4);
        s.x += lsum[row][o4 + 0];
        s.y += lsum[row][o4 + 1];
        s.z += lsum[row][o4 + 2];
        s.w += lsum[row][o4 + 3];
        float* fb = feat + (size_t)grow * 3072 + 64 * 32 + o4;
        #pragma unroll
        for (int fc = 0; fc < 32; ++fc) {
            float val = (float)tv[row][64 + fc];
            float m   = (float)tm[row][64 + fc];
            float vk = val * (1.f - m);
            float4 cl4 = *(const float4*)(cat_linear + fc * 32 + o4);
            float4 r;
            r.x = cl4.x * vk; r.y = cl4.y * vk; r.z = cl4.z * vk; r.w = cl4.w * vk;
            if (fc < 8) {
                float4 mb4 = *(const float4*)(memb + fc * 32 + o4);
                r.x = fmaf(mb4.x, m, r.x);
                r.y = fmaf(mb4.y, m, r.y);
                r.z = fmaf(mb4.z, m, r.z);
                r.w = fmaf(mb4.w, m, r.w);
            }
            *(float4*)(fb + fc * 32) = r;
            s.x += r.x; s.y += r.y; s.z += r.z; s.w += r.w;
        }
        *(float4*)(logits + (size_t)grow * 32 + o4) = s;
    }
}

extern "C" void kernel_launch(void* const* d_in, const int* in_sizes, int n_in,
                              void* d_out, int out_size, void* d_ws, size_t ws_size,
                              hipStream_t stream) {
    const float* tab        = (const float*)d_in[0];
    const float* v0         = (const float*)d_in[1];
    const float* g0         = (const float*)d_in[2];
    const float* b0         = (const float*)d_in[3];
    const float* v1         = (const float*)d_in[4];
    const float* g1         = (const float*)d_in[5];
    const float* b1         = (const float*)d_in[6];
    const float* v2         = (const float*)d_in[7];
    const float* g2         = (const float*)d_in[8];
    const float* b2         = (const float*)d_in[9];
    const float* v3         = (const float*)d_in[10];
    const float* g3         = (const float*)d_in[11];
    const float* cat_linear = (const float*)d_in[12];
    const float* memb       = (const float*)d_in[13];
    const float* bias       = (const float*)d_in[14];

    float* out    = (float*)d_out;
    float* logits = out;                 // [8192][32]
    float* feat   = out + LOGN;          // [8192][96][32]

    float* ws   = (float*)d_ws;
    float* w0   = (float*)((char*)d_ws + OFF_W0);
    f16*   b1f  = (f16*)((char*)d_ws + OFF_B1);
    f16*   b2f  = (f16*)((char*)d_ws + OFF_B2);
    f16*   b3f  = (f16*)((char*)d_ws + OFF_B3);

    prep_norm<<<48, 256, 0, stream>>>(v0, g0, v1, g1, v2, g2, v3, g3, ws);
    prep_frag<<<1792, 256, 0, stream>>>(v1, v2, v3, ws, b1f, b2f, b3f);

    nam_fused<<<256, 256, 0, stream>>>(tab, w0, b1f, b2f, b3f, b0, b1, b2,
                                       memb, cat_linear, bias, feat, logits);
}